// Round 1
// baseline (246.463 us; speedup 1.0000x reference)
//
#include <hip/hip_runtime.h>
#include <hip/hip_bf16.h>

#define N_NODES 262144
#define NUM_C   256
#define DIM     128
#define NUM_G   128
#define GMAX    8

typedef short  bf16x8 __attribute__((ext_vector_type(8)));
typedef float  f32x4  __attribute__((ext_vector_type(4)));

__device__ __forceinline__ short f2b(float f) {
    __hip_bfloat16 h = __float2bfloat16(f);
    return *reinterpret_cast<short*>(&h);
}

// ---------------------------------------------------------------------------
// Prep: zero out, convert W fp32->bf16, compute c_sq (fp32), build cum_end[g]
// (cumulative node count through graph g) from the sorted batch array.
// Grid: 128 blocks x 256 threads. Block b handles W rows 2b, 2b+1 and
// out elements [b*256, b*256+256); each thread scans 8 batch entries.
// ---------------------------------------------------------------------------
__global__ void centroid_prep(const float* __restrict__ W,
                              const int* __restrict__ batch,
                              float* __restrict__ out,
                              short* __restrict__ Wb,
                              float* __restrict__ csq,
                              int* __restrict__ cum_end)
{
    const int t   = threadIdx.x;
    const int b   = blockIdx.x;
    const int gid = b * 256 + t;

    float w = W[gid];
    out[gid] = 0.f;
    Wb[gid] = f2b(w);

    __shared__ float red[256];
    red[t] = w * w;
    __syncthreads();
    for (int off = 64; off > 0; off >>= 1) {
        if ((t & 127) < off) red[t] += red[t + off];
        __syncthreads();
    }
    if (t == 0)   csq[2 * b]     = red[0];
    if (t == 128) csq[2 * b + 1] = red[128];

    // cum_end: thread scans batch[i0 .. i0+8], writes run boundaries.
    long i0 = (long)gid * 8;
    int g = batch[i0];
    if (gid == 0) {
        for (int gg = 0; gg < g; ++gg) cum_end[gg] = 0;
    }
    for (int k = 0; k < 8; ++k) {
        long i = i0 + k;
        int gn = (i + 1 < N_NODES) ? batch[i + 1] : NUM_G;
        if (gn != g) {
            for (int gg = g; gg < gn; ++gg) cum_end[gg] = (int)(i + 1);
        }
        g = gn;
    }
}

// ---------------------------------------------------------------------------
// Main: 1024 blocks x 256 threads. Block = 256 nodes, wave = 64 nodes.
// A-fragments (x, bf16) held in registers for all 64 nodes; loop over 16
// column tiles of 16 centroids, B-fragments loaded from bf16 W (L2-resident).
// dist = sqrt(max(xsq + csq - 2*cross, 0)); pooled via wave butterfly ->
// block LDS accumulator (graphs [gmin, gmin+span)) -> global atomics.
// ---------------------------------------------------------------------------
__global__ __launch_bounds__(256, 2) void centroid_main(
    const float* __restrict__ x,
    const int* __restrict__ batch,
    const short* __restrict__ Wb,
    const float* __restrict__ csq,
    float* __restrict__ out)
{
    __shared__ float lacc[GMAX * NUM_C];
    const int t  = threadIdx.x;
    const int nb = blockIdx.x << 8;   // first node of this block

    for (int i = t; i < GMAX * NUM_C; i += 256) lacc[i] = 0.f;
    __syncthreads();

    // batch is sorted: block's graph range
    const int gmin = batch[nb];
    const int span = batch[nb + 255] - gmin + 1;
    const bool use_lds = (span <= GMAX);

    const int lane  = t & 63;
    const int m16   = lane & 15;
    const int quad  = lane >> 4;
    const int wbase = nb + (t >> 6) * 64;   // this wave's 64 nodes

    // ---- load A fragments + row sum-of-squares (fp32) ----
    bf16x8 afrag[4][4];
    float  xsq[4];
#pragma unroll
    for (int s = 0; s < 4; ++s) {
        const float* xp = x + (long)(wbase + s * 16 + m16) * DIM + quad * 8;
        float ss = 0.f;
#pragma unroll
        for (int ks = 0; ks < 4; ++ks) {
            f32x4 u0 = *(const f32x4*)(xp + ks * 32);
            f32x4 u1 = *(const f32x4*)(xp + ks * 32 + 4);
            bf16x8 a;
#pragma unroll
            for (int j = 0; j < 4; ++j) {
                ss += u0[j] * u0[j] + u1[j] * u1[j];
                a[j]     = f2b(u0[j]);
                a[j + 4] = f2b(u1[j]);
            }
            afrag[s][ks] = a;
        }
        ss += __shfl_xor(ss, 16);
        ss += __shfl_xor(ss, 32);
        xsq[s] = ss;   // lane holds row (l&15) of subtile s
    }

    // xsq re-distributed to D-layout rows (quad*4 + r)
    float xsqr[4][4];
#pragma unroll
    for (int s = 0; s < 4; ++s)
#pragma unroll
        for (int r = 0; r < 4; ++r)
            xsqr[s][r] = __shfl(xsq[s], quad * 4 + r);

    // per-subtile graph info (batch sorted => uniform iff ends equal)
    int  gfirst[4];
    bool guni[4];
#pragma unroll
    for (int s = 0; s < 4; ++s) {
        int g0 = batch[wbase + s * 16];
        int g1 = batch[wbase + s * 16 + 15];
        gfirst[s] = g0;
        guni[s]   = (g0 == g1);
    }

    // ---- column-tile loop ----
#pragma unroll 1
    for (int ct = 0; ct < 16; ++ct) {
        const int c = ct * 16 + m16;
        bf16x8 bfrag[4];
        const short* wp = Wb + c * DIM + quad * 8;
#pragma unroll
        for (int ks = 0; ks < 4; ++ks)
            bfrag[ks] = *(const bf16x8*)(wp + ks * 32);
        const float cs = csq[c];

#pragma unroll
        for (int s = 0; s < 4; ++s) {
            f32x4 acc = {0.f, 0.f, 0.f, 0.f};
#pragma unroll
            for (int ks = 0; ks < 4; ++ks)
                acc = __builtin_amdgcn_mfma_f32_16x16x32_bf16(
                          afrag[s][ks], bfrag[ks], acc, 0, 0, 0);

            if (use_lds && guni[s]) {
                float v = 0.f;
#pragma unroll
                for (int r = 0; r < 4; ++r) {
                    float d2 = xsqr[s][r] + cs - 2.f * acc[r];
                    v += sqrtf(fmaxf(d2, 0.f));
                }
                v += __shfl_xor(v, 16);
                v += __shfl_xor(v, 32);
                if (quad == 0)
                    atomicAdd(&lacc[(gfirst[s] - gmin) * NUM_C + c], v);
            } else {
#pragma unroll
                for (int r = 0; r < 4; ++r) {
                    int   row = wbase + s * 16 + quad * 4 + r;
                    int   g   = batch[row];
                    float d2  = xsqr[s][r] + cs - 2.f * acc[r];
                    float d   = sqrtf(fmaxf(d2, 0.f));
                    if (use_lds) atomicAdd(&lacc[(g - gmin) * NUM_C + c], d);
                    else         atomicAdd(&out[g * NUM_C + c], d);
                }
            }
        }
    }

    __syncthreads();
    if (use_lds) {
        for (int i = t; i < span * NUM_C; i += 256)
            atomicAdd(&out[(gmin + (i >> 8)) * NUM_C + (i & 255)], lacc[i]);
    }
}

// ---------------------------------------------------------------------------
// Finish: divide sums by per-graph counts. Grid: 128 blocks x 256 threads.
// ---------------------------------------------------------------------------
__global__ void centroid_finish(float* __restrict__ out,
                                const int* __restrict__ cum_end)
{
    const int g = blockIdx.x;
    const int c = threadIdx.x;
    int cnt = cum_end[g] - (g ? cum_end[g - 1] : 0);
    float denom = (float)(cnt > 0 ? cnt : 1);
    out[g * NUM_C + c] /= denom;
}

extern "C" void kernel_launch(void* const* d_in, const int* in_sizes, int n_in,
                              void* d_out, int out_size, void* d_ws, size_t ws_size,
                              hipStream_t stream) {
    const float* x     = (const float*)d_in[0];
    const int*   batch = (const int*)d_in[1];
    const float* W     = (const float*)d_in[2];
    float*       out   = (float*)d_out;

    // workspace: Wb (64 KB) | csq (1 KB) | cum_end (512 B)
    short* Wb      = (short*)d_ws;
    float* csq     = (float*)((char*)d_ws + 65536);
    int*   cum_end = (int*)((char*)d_ws + 65536 + 1024);

    centroid_prep<<<128, 256, 0, stream>>>(W, batch, out, Wb, csq, cum_end);
    centroid_main<<<N_NODES / 256, 256, 0, stream>>>(x, batch, Wb, csq, out);
    centroid_finish<<<NUM_G, 256, 0, stream>>>(out, cum_end);
}